// Round 1
// baseline (46468.134 us; speedup 1.0000x reference)
//
#include <hip/hip_runtime.h>
#include <math.h>

// DIORA forward, MI355X. B=32, T=40, D_IN=1024, D=400.
// Key algebraic restructure: concat([hl,hr])@W = hl@W_top + hr@W_bot, and
// hl@S@hr = (hl@S)·hr  -> precompute per-cell transforms once, per-pair work
// becomes elementwise add + dot.
//
// State layout: d_out is (32, 820, 802) fp32: [h_in(400) | s_in(1) | h_out(400) | s_out(1)]
// d_ws: 3 arrays (32, 820, 400) fp32 = ~126 MB:
//   inside pass : hA = h@W_in_top, hB = h@W_in_bot, hC = h@S_in
//   outside pass: hA = h_out@W_out_top, hB = h_in@W_out_bot, hC = h_out@S_out

#define TLEN 40
#define DD 400
#define NCELL 820
#define STR 802
#define RB 8          // batches per block
#define NBATCH 32

__device__ __forceinline__ int coff(int l) { return l * TLEN - (l * (l - 1)) / 2; }

// ---------------- fused compose + transform for one level ----------------
template<int INSIDE>
__global__ __launch_bounds__(256)
void level_kernel(int lv,
                  float* obuf,                       // d_out state
                  float* hA, float* hB, float* hC,   // transform arrays
                  const float* __restrict__ Wpair,   // (2*DD, DD)
                  const float* __restrict__ bias,    // (DD)
                  const float* __restrict__ Smat)    // (DD, DD)
{
    const int nk   = INSIDE ? lv : (TLEN - 1 - lv);
    const int pos  = blockIdx.x >> 2;
    const int bg   = (blockIdx.x & 3) * RB;
    const int cell = coff(lv) + pos;
    const int tid  = threadIdx.x;

    __shared__ int   i1s[TLEN], i2s[TLEN];
    __shared__ float sbs[RB][TLEN];
    __shared__ float ps[RB][TLEN];
    __shared__ float hnew[RB][DD];
    __shared__ float snew[RB];
    __shared__ float rinv[RB];

    // phase 0: pair indices (shared across batches)
    if (tid < nk) {
        int k = tid, i1, i2;
        if (INSIDE) {
            i1 = coff(k) + pos;
            i2 = coff(lv - k - 1) + pos + k + 1;
        } else {
            if (k < pos) { i1 = coff(lv + k + 1) + pos - k - 1; i2 = coff(k) + pos - k - 1; }
            else         { int j = k - pos; i1 = coff(lv + j + 1) + pos; i2 = coff(j) + pos + lv + 1; }
        }
        i1s[k] = i1; i2s[k] = i2;
    }
    __syncthreads();

    // phase 1: scores  sb = dot(hC[i1], h_in[i2]) + s1[i1] + s_in[i2]
    {
        int g = tid >> 4, gl = tid & 15;
        for (int item = g; item < RB * nk; item += 16) {
            int bl = item / nk, k = item - bl * nk;
            int b = bg + bl;
            const float* v1 = hC   + (b * NCELL + i1s[k]) * DD;
            const float* v2 = obuf + (b * NCELL + i2s[k]) * STR;   // h_in
            float acc = 0.f;
            for (int j = gl; j < DD; j += 16) acc += v1[j] * v2[j];
            acc += __shfl_xor(acc, 8);
            acc += __shfl_xor(acc, 4);
            acc += __shfl_xor(acc, 2);
            acc += __shfl_xor(acc, 1);
            if (gl == 0) {
                float st;
                if (INSIDE)
                    st = obuf[(b*NCELL + i1s[k])*STR + DD] + obuf[(b*NCELL + i2s[k])*STR + DD];
                else
                    st = obuf[(b*NCELL + i1s[k])*STR + (STR-1)] + obuf[(b*NCELL + i2s[k])*STR + DD];
                sbs[bl][k] = acc + st;
            }
        }
    }
    __syncthreads();

    // phase 2: softmax per (batch) row, one wave per row
    {
        int w = tid >> 6, lane = tid & 63;
        for (int bl = w; bl < RB; bl += 4) {
            float v = (lane < nk) ? sbs[bl][lane] : -INFINITY;
            float m = v;
            #pragma unroll
            for (int o = 32; o; o >>= 1) m = fmaxf(m, __shfl_xor(m, o));
            float e = (lane < nk) ? __expf(v - m) : 0.f;
            float s = e;
            #pragma unroll
            for (int o = 32; o; o >>= 1) s += __shfl_xor(s, o);
            float p = e / s;
            if (lane < nk) ps[bl][lane] = p;
            float pv = (lane < nk) ? p * v : 0.f;
            #pragma unroll
            for (int o = 32; o; o >>= 1) pv += __shfl_xor(pv, o);
            if (lane == 0) snew[bl] = pv;
        }
    }
    __syncthreads();

    // phase 3: h_new = sum_k p_k * relu(hA[i1] + hB[i2] + bias)
    for (int t = tid; t < RB * DD; t += 256) {
        int bl = t / DD, f = t - bl * DD;
        int b = bg + bl;
        float bf = bias[f];
        float acc = 0.f;
        for (int k = 0; k < nk; ++k) {
            float hv = hA[(b*NCELL + i1s[k])*DD + f] + hB[(b*NCELL + i2s[k])*DD + f] + bf;
            acc += ps[bl][k] * fmaxf(hv, 0.f);
        }
        hnew[bl][f] = acc;
    }
    __syncthreads();

    // phase 4: norms
    {
        int w = tid >> 6, lane = tid & 63;
        for (int bl = w; bl < RB; bl += 4) {
            float ss = 0.f;
            for (int f = lane; f < DD; f += 64) { float v = hnew[bl][f]; ss += v * v; }
            #pragma unroll
            for (int o = 32; o; o >>= 1) ss += __shfl_xor(ss, o);
            if (lane == 0) rinv[bl] = 1.f / (sqrtf(ss) + 1e-8f);
        }
    }
    __syncthreads();

    // write h, s; keep normalized h in LDS for transforms
    const int hoff = INSIDE ? 0 : (DD + 1);
    const int soff = INSIDE ? DD : (STR - 1);
    for (int t = tid; t < RB * DD; t += 256) {
        int bl = t / DD, f = t - bl * DD;
        float v = hnew[bl][f] * rinv[bl];
        hnew[bl][f] = v;
        obuf[((bg + bl)*NCELL + cell)*STR + hoff + f] = v;
    }
    if (tid < RB) obuf[((bg + tid)*NCELL + cell)*STR + soff] = snew[tid];
    __syncthreads();

    // phase 5: transforms of the new cells (skip when never used as child/parent)
    const bool doT = INSIDE ? (lv < TLEN - 1) : (lv > 0);
    if (doT) {
        const int NM = INSIDE ? 3 : 2;
        for (int t = tid; t < RB * NM * DD; t += 256) {
            int bl = t / (NM * DD);
            int r  = t - bl * (NM * DD);
            int m  = r / DD, c = r - m * DD;
            const float* M;
            float* dst;
            if (INSIDE) {
                M   = (m == 0) ? Wpair : ((m == 1) ? (Wpair + DD*DD) : Smat);
                dst = (m == 0) ? hA    : ((m == 1) ? hB : hC);
            } else {
                M   = (m == 0) ? Wpair : Smat;
                dst = (m == 0) ? hA    : hC;
            }
            float acc = 0.f;
            #pragma unroll 4
            for (int i = 0; i < DD; ++i) acc += hnew[bl][i] * M[i*DD + c];
            dst[((bg + bl)*NCELL + cell)*DD + c] = acc;
        }
    }
}

// ---------------- leaf: h = unit(relu(x @ W_leaf + b)) + inside transforms ----------------
__global__ __launch_bounds__(256)
void leaf_kernel(const float* __restrict__ x, const float* __restrict__ Wl,
                 const float* __restrict__ blf, const float* __restrict__ Win,
                 const float* __restrict__ Sin,
                 float* obuf, float* hA, float* hB, float* hC)
{
    const int pos = blockIdx.x >> 2;
    const int bg  = (blockIdx.x & 3) * RB;
    const int tid = threadIdx.x;
    __shared__ float xs[RB][1024];
    __shared__ float hnew[RB][DD];
    __shared__ float rinv[RB];

    for (int t = tid; t < RB * 1024; t += 256) {
        int bl = t >> 10, i = t & 1023;
        xs[bl][i] = x[((bg + bl) * TLEN + pos) * 1024 + i];
    }
    __syncthreads();

    for (int t = tid; t < RB * DD; t += 256) {
        int bl = t / DD, f = t - bl * DD;
        float acc = blf[f];
        #pragma unroll 4
        for (int i = 0; i < 1024; ++i) acc += xs[bl][i] * Wl[i*DD + f];
        hnew[bl][f] = fmaxf(acc, 0.f);
    }
    __syncthreads();

    {
        int w = tid >> 6, lane = tid & 63;
        for (int bl = w; bl < RB; bl += 4) {
            float ss = 0.f;
            for (int f = lane; f < DD; f += 64) { float v = hnew[bl][f]; ss += v * v; }
            #pragma unroll
            for (int o = 32; o; o >>= 1) ss += __shfl_xor(ss, o);
            if (lane == 0) rinv[bl] = 1.f / (sqrtf(ss) + 1e-8f);
        }
    }
    __syncthreads();

    for (int t = tid; t < RB * DD; t += 256) {
        int bl = t / DD, f = t - bl * DD;
        float v = hnew[bl][f] * rinv[bl];
        hnew[bl][f] = v;
        obuf[((bg + bl)*NCELL + pos)*STR + f] = v;
    }
    if (tid < RB) obuf[((bg + tid)*NCELL + pos)*STR + DD] = 0.f;   // s_in(leaf)=0
    __syncthreads();

    for (int t = tid; t < RB * 3 * DD; t += 256) {
        int bl = t / (3 * DD);
        int r  = t - bl * 3 * DD;
        int m  = r / DD, c = r - m * DD;
        const float* M = (m == 0) ? Win : ((m == 1) ? (Win + DD*DD) : Sin);
        float* dst     = (m == 0) ? hA  : ((m == 1) ? hB : hC);
        float acc = 0.f;
        #pragma unroll 4
        for (int i = 0; i < DD; ++i) acc += hnew[bl][i] * M[i*DD + c];
        dst[((bg + bl)*NCELL + pos)*DD + c] = acc;
    }
}

// ---------------- hB = h_in @ W_out_bot for all cells ----------------
__global__ __launch_bounds__(256)
void prep_out_kernel(const float* obuf, const float* __restrict__ Wout, float* hB)
{
    const int cell = blockIdx.x >> 2;
    const int bg   = (blockIdx.x & 3) * RB;
    const int tid  = threadIdx.x;
    __shared__ float hs[RB][DD];
    for (int t = tid; t < RB * DD; t += 256) {
        int bl = t / DD, f = t - bl * DD;
        hs[bl][f] = obuf[((bg + bl)*NCELL + cell)*STR + f];
    }
    __syncthreads();
    const float* Wb = Wout + DD*DD;
    for (int t = tid; t < RB * DD; t += 256) {
        int bl = t / DD, c = t - bl * DD;
        float acc = 0.f;
        #pragma unroll 4
        for (int i = 0; i < DD; ++i) acc += hs[bl][i] * Wb[i*DD + c];
        hB[((bg + bl)*NCELL + cell)*DD + c] = acc;
    }
}

// ---------------- root: h_out[819] = unit(root_h), s_out=0, + out transforms ----------------
__global__ __launch_bounds__(256)
void root_kernel(const float* __restrict__ rooth, const float* __restrict__ Wout,
                 const float* __restrict__ Sout, float* obuf, float* hA, float* hC)
{
    const int bg  = blockIdx.x * RB;
    const int tid = threadIdx.x;
    __shared__ float us[DD];
    __shared__ float red[4];
    int w = tid >> 6, lane = tid & 63;
    float ss = 0.f;
    for (int f = tid; f < DD; f += 256) { float v = rooth[f]; ss += v * v; }
    #pragma unroll
    for (int o = 32; o; o >>= 1) ss += __shfl_xor(ss, o);
    if (lane == 0) red[w] = ss;
    __syncthreads();
    float ri = 1.f / (sqrtf(red[0] + red[1] + red[2] + red[3]) + 1e-8f);
    for (int f = tid; f < DD; f += 256) us[f] = rooth[f] * ri;
    __syncthreads();

    const int cell = NCELL - 1;
    for (int t = tid; t < RB * DD; t += 256) {
        int bl = t / DD, f = t - bl * DD;
        obuf[((bg + bl)*NCELL + cell)*STR + DD + 1 + f] = us[f];
    }
    if (tid < RB) obuf[((bg + tid)*NCELL + cell)*STR + (STR-1)] = 0.f;

    for (int t = tid; t < RB * 2 * DD; t += 256) {
        int bl = t / (2 * DD);
        int r  = t - bl * 2 * DD;
        int m  = r / DD, c = r - m * DD;
        const float* M = m ? Sout : Wout;
        float* dst     = m ? hC   : hA;
        float acc = 0.f;
        #pragma unroll 4
        for (int i = 0; i < DD; ++i) acc += us[i] * M[i*DD + c];
        dst[((bg + bl)*NCELL + cell)*DD + c] = acc;
    }
}

extern "C" void kernel_launch(void* const* d_in, const int* in_sizes, int n_in,
                              void* d_out, int out_size, void* d_ws, size_t ws_size,
                              hipStream_t stream)
{
    const float* x     = (const float*)d_in[0];
    const float* Wl    = (const float*)d_in[1];
    const float* blf   = (const float*)d_in[2];
    const float* Win   = (const float*)d_in[3];
    const float* bin   = (const float*)d_in[4];
    const float* Sin   = (const float*)d_in[5];
    const float* Wout  = (const float*)d_in[6];
    const float* bout  = (const float*)d_in[7];
    const float* Sout  = (const float*)d_in[8];
    const float* rooth = (const float*)d_in[9];

    float* obuf = (float*)d_out;
    float* hA = (float*)d_ws;                       // needs 3*32*820*400*4 = ~126 MB
    size_t NB = (size_t)NBATCH * NCELL * DD;
    float* hB = hA + NB;
    float* hC = hB + NB;

    // inside pass
    leaf_kernel<<<TLEN * 4, 256, 0, stream>>>(x, Wl, blf, Win, Sin, obuf, hA, hB, hC);
    for (int lv = 1; lv < TLEN; ++lv)
        level_kernel<1><<<(TLEN - lv) * 4, 256, 0, stream>>>(lv, obuf, hA, hB, hC, Win, bin, Sin);

    // outside pass
    prep_out_kernel<<<NCELL * 4, 256, 0, stream>>>(obuf, Wout, hB);
    root_kernel<<<NBATCH / RB, 256, 0, stream>>>(rooth, Wout, Sout, obuf, hA, hC);
    for (int lv = TLEN - 2; lv >= 0; --lv)
        level_kernel<0><<<(TLEN - lv) * 4, 256, 0, stream>>>(lv, obuf, hA, hB, hC, Wout, bout, Sout);
}

// Round 2
// 4536.844 us; speedup vs baseline: 10.2424x; 10.2424x over previous
//
#include <hip/hip_runtime.h>
#include <math.h>

// DIORA forward, MI355X. B=32, T=40, D_IN=1024, D=400.
// Restructured: per-level compose kernel (L*32 blocks) + tiled SGEMM for
// per-cell transforms. hT (32,820,1200) holds, per cell:
//   inside : [0,400)=h@W_in_top  [400,800)=h@W_in_bot  [800,1200)=h@S_in
//   outside: [0,400)=ho@W_out_top [400,800)=ho@S_out   [800,1200)=h_in@W_out_bot (prep)
// obuf (32,820,802): [h_in 400 | s_in 1 | h_out 400 | s_out 1]
// Leaf GEMM scratch aliases obuf h_out fields of flat rows 0..1279 (written
// much later by the outside pass).

#define TLEN 40
#define DD 400
#define NCELL 820
#define STR 802

__device__ __forceinline__ int coff(int l) { return l * TLEN - (l * (l - 1)) / 2; }

// ---------------- generic 64x64x16 fp32 tiled GEMM ----------------
// MODE 0 (leaf): A = x (row stride K), C = obuf + row*STR + (DD+1), bias+relu
// MODE 1 (trans): A = obuf cell rows (+hoff), C = hT + cellrow*1200 + co
template<int MODE>
__global__ __launch_bounds__(256)
void gemm_kernel(const float* __restrict__ A0,
                 const float* __restrict__ B0, const float* __restrict__ B1,
                 const float* __restrict__ B2,
                 const float* __restrict__ bias,
                 float* __restrict__ C0,
                 int M, int Ntot, int K, int L, int cb, int hoff, int co)
{
    __shared__ float As[16][68];
    __shared__ float Bs[16][68];
    const int tid = threadIdx.x;
    const int bm = blockIdx.x, bn = blockIdx.y;

    const int ar = tid >> 2;          // A tile row 0..63
    const int ak = (tid & 3) << 2;    // A k offset {0,4,8,12}
    const int bk = tid >> 4;          // B k row 0..15
    const int bc = (tid & 15) << 2;   // B col offset

    const int row = bm * 64 + ar;
    const float* Ap = nullptr;
    if (row < M) {
        if (MODE == 0) Ap = A0 + (size_t)row * K;
        else { int b = row / L, p = row - b * L;
               Ap = A0 + ((size_t)(b * NCELL) + cb + p) * STR + hoff; }
    }
    const int nB = bn * 64 + bc;
    const float* Bp = nullptr;
    if (nB < Ntot) {
        int mat = nB / DD;
        const float* Bm = (mat == 0) ? B0 : ((mat == 1) ? B1 : B2);
        Bp = Bm + (nB - mat * DD);
    }

    float acc[4][4];
    #pragma unroll
    for (int i = 0; i < 4; ++i)
        #pragma unroll
        for (int j = 0; j < 4; ++j) acc[i][j] = 0.f;

    const int ty = tid >> 4, tx = tid & 15;

    for (int k0 = 0; k0 < K; k0 += 16) {
        float a0 = 0.f, a1 = 0.f, a2 = 0.f, a3 = 0.f;
        if (Ap) { const float* p = Ap + k0 + ak; a0 = p[0]; a1 = p[1]; a2 = p[2]; a3 = p[3]; }
        float4 bv = make_float4(0.f, 0.f, 0.f, 0.f);
        if (Bp) bv = *(const float4*)(Bp + (size_t)(k0 + bk) * DD);

        As[ak + 0][ar] = a0; As[ak + 1][ar] = a1;
        As[ak + 2][ar] = a2; As[ak + 3][ar] = a3;
        *(float4*)&Bs[bk][bc] = bv;
        __syncthreads();

        #pragma unroll
        for (int k = 0; k < 16; ++k) {
            float4 a = *(const float4*)&As[k][ty * 4];
            float4 b = *(const float4*)&Bs[k][tx * 4];
            float ar_[4] = {a.x, a.y, a.z, a.w};
            float br_[4] = {b.x, b.y, b.z, b.w};
            #pragma unroll
            for (int i = 0; i < 4; ++i)
                #pragma unroll
                for (int j = 0; j < 4; ++j) acc[i][j] += ar_[i] * br_[j];
        }
        __syncthreads();
    }

    #pragma unroll
    for (int i = 0; i < 4; ++i) {
        int r = bm * 64 + ty * 4 + i;
        if (r >= M) continue;
        size_t crow;
        if (MODE == 0) crow = (size_t)r * STR + (DD + 1);
        else { int b = r / L, p = r - b * L;
               crow = ((size_t)(b * NCELL) + cb + p) * 1200 + co; }
        #pragma unroll
        for (int j = 0; j < 4; ++j) {
            int n = bn * 64 + tx * 4 + j;
            if (n >= Ntot) continue;
            float v = acc[i][j];
            if (MODE == 0) v = fmaxf(v + bias[n], 0.f);
            C0[crow + n] = v;
        }
    }
}

// ---------------- normalize leaf rows (reads GEMM scratch in h_out fields) ----
__global__ __launch_bounds__(256)
void unit_leaf(float* obuf)
{
    int w = threadIdx.x >> 6, lane = threadIdx.x & 63;
    int r = blockIdx.x * 4 + w;                 // x-row 0..1279
    const float* t = obuf + (size_t)r * STR + (DD + 1);
    float ss = 0.f;
    for (int f = lane; f < DD; f += 64) { float v = t[f]; ss += v * v; }
    #pragma unroll
    for (int o = 32; o; o >>= 1) ss += __shfl_xor(ss, o);
    float rinv = 1.f / (sqrtf(ss) + 1e-8f);
    int b = r / TLEN, pos = r - b * TLEN;
    size_t orow = ((size_t)(b * NCELL) + pos) * STR;
    for (int f = lane; f < DD; f += 64) obuf[orow + f] = t[f] * rinv;
    if (lane == 0) obuf[orow + DD] = 0.f;       // s_in(leaf)=0
}

// ---------------- per-level compose ----------------
template<int INSIDE>
__global__ __launch_bounds__(256)
void compose_kernel(int lv, float* obuf, const float* __restrict__ hT,
                    const float* __restrict__ bias)
{
    const int nk  = INSIDE ? lv : (TLEN - 1 - lv);
    const int b   = blockIdx.x & 31;
    const int pos = blockIdx.x >> 5;
    const int cell = coff(lv) + pos;
    const int tid = threadIdx.x;

    __shared__ int   i1s[TLEN], i2s[TLEN];
    __shared__ float sbs[TLEN], ps[TLEN];
    __shared__ float hnew[DD];
    __shared__ float red[4];
    __shared__ float sh_snew;

    if (tid < nk) {
        int k = tid, i1, i2;
        if (INSIDE) {
            i1 = coff(k) + pos;
            i2 = coff(lv - k - 1) + pos + k + 1;
        } else {
            if (k < pos) { i1 = coff(lv + k + 1) + pos - k - 1; i2 = coff(k) + pos - k - 1; }
            else         { int j = k - pos; i1 = coff(lv + j + 1) + pos; i2 = coff(j) + pos + lv + 1; }
        }
        i1s[k] = i1; i2s[k] = i2;
    }
    __syncthreads();

    // scores: one 16-lane group per k
    {
        const int g = tid >> 4, gl = tid & 15;
        const int sco = INSIDE ? 800 : 400;
        for (int k = g; k < nk; k += 16) {
            const float* v1 = hT + ((size_t)(b * NCELL) + i1s[k]) * 1200 + sco;
            const float* v2 = obuf + ((size_t)(b * NCELL) + i2s[k]) * STR;
            float acc = 0.f;
            for (int j = gl; j < DD; j += 16) acc += v1[j] * v2[j];
            acc += __shfl_xor(acc, 8);
            acc += __shfl_xor(acc, 4);
            acc += __shfl_xor(acc, 2);
            acc += __shfl_xor(acc, 1);
            if (gl == 0) {
                float st;
                if (INSIDE)
                    st = obuf[((size_t)(b * NCELL) + i1s[k]) * STR + DD]
                       + obuf[((size_t)(b * NCELL) + i2s[k]) * STR + DD];
                else
                    st = obuf[((size_t)(b * NCELL) + i1s[k]) * STR + (STR - 1)]
                       + obuf[((size_t)(b * NCELL) + i2s[k]) * STR + DD];
                sbs[k] = acc + st;
            }
        }
    }
    __syncthreads();

    // softmax (wave 0), also s_new = sum p*sb
    if (tid < 64) {
        float v = (tid < nk) ? sbs[tid] : -INFINITY;
        float m = v;
        #pragma unroll
        for (int o = 32; o; o >>= 1) m = fmaxf(m, __shfl_xor(m, o));
        float e = (tid < nk) ? __expf(v - m) : 0.f;
        float s = e;
        #pragma unroll
        for (int o = 32; o; o >>= 1) s += __shfl_xor(s, o);
        float p = e / s;
        if (tid < nk) ps[tid] = p;
        float pv = (tid < nk) ? p * v : 0.f;
        #pragma unroll
        for (int o = 32; o; o >>= 1) pv += __shfl_xor(pv, o);
        if (tid == 0) sh_snew = pv;
    }
    __syncthreads();

    // h_new = sum_k p_k * relu(hA[i1] + hB[i2] + bias)
    {
        const int bco = INSIDE ? 400 : 800;
        for (int f = tid; f < DD; f += 256) {
            float bf = bias[f];
            float acc = 0.f;
            for (int k = 0; k < nk; ++k) {
                float hv = hT[((size_t)(b * NCELL) + i1s[k]) * 1200 + f]
                         + hT[((size_t)(b * NCELL) + i2s[k]) * 1200 + bco + f] + bf;
                acc += ps[k] * fmaxf(hv, 0.f);
            }
            hnew[f] = acc;
        }
    }
    __syncthreads();

    // norm
    float ss = 0.f;
    for (int f = tid; f < DD; f += 256) { float v = hnew[f]; ss += v * v; }
    #pragma unroll
    for (int o = 32; o; o >>= 1) ss += __shfl_xor(ss, o);
    if ((tid & 63) == 0) red[tid >> 6] = ss;
    __syncthreads();
    float rinv = 1.f / (sqrtf(red[0] + red[1] + red[2] + red[3]) + 1e-8f);

    const int hoff = INSIDE ? 0 : (DD + 1);
    const int soff = INSIDE ? DD : (STR - 1);
    size_t orow = ((size_t)(b * NCELL) + cell) * STR;
    for (int f = tid; f < DD; f += 256) obuf[orow + hoff + f] = hnew[f] * rinv;
    if (tid == 0) obuf[orow + soff] = sh_snew;
}

// ---------------- root: h_out[819]=unit(root_h) (same for all b) + transforms ---
__global__ __launch_bounds__(256)
void root_kernel(const float* __restrict__ rooth, const float* __restrict__ Wout,
                 const float* __restrict__ Sout, float* obuf, float* __restrict__ hT)
{
    const int b = blockIdx.x;
    const int tid = threadIdx.x;
    __shared__ float u[DD];
    __shared__ float red[4];
    float ss = 0.f;
    for (int f = tid; f < DD; f += 256) { float v = rooth[f]; ss += v * v; }
    #pragma unroll
    for (int o = 32; o; o >>= 1) ss += __shfl_xor(ss, o);
    if ((tid & 63) == 0) red[tid >> 6] = ss;
    __syncthreads();
    float rinv = 1.f / (sqrtf(red[0] + red[1] + red[2] + red[3]) + 1e-8f);
    for (int f = tid; f < DD; f += 256) u[f] = rooth[f] * rinv;
    __syncthreads();

    size_t orow = ((size_t)(b * NCELL) + NCELL - 1) * STR;
    for (int f = tid; f < DD; f += 256) obuf[orow + DD + 1 + f] = u[f];
    if (tid == 0) obuf[orow + STR - 1] = 0.f;

    size_t trow = ((size_t)(b * NCELL) + NCELL - 1) * 1200;
    for (int n = tid; n < 800; n += 256) {
        const float* Mp = (n < DD) ? Wout : Sout;
        int c = (n < DD) ? n : n - DD;
        float acc = 0.f;
        #pragma unroll 4
        for (int k = 0; k < DD; ++k) acc += u[k] * Mp[k * DD + c];
        hT[trow + n] = acc;
    }
}

extern "C" void kernel_launch(void* const* d_in, const int* in_sizes, int n_in,
                              void* d_out, int out_size, void* d_ws, size_t ws_size,
                              hipStream_t stream)
{
    const float* x     = (const float*)d_in[0];
    const float* Wl    = (const float*)d_in[1];
    const float* blf   = (const float*)d_in[2];
    const float* Win   = (const float*)d_in[3];
    const float* bin   = (const float*)d_in[4];
    const float* Sin   = (const float*)d_in[5];
    const float* Wout  = (const float*)d_in[6];
    const float* bout  = (const float*)d_in[7];
    const float* Sout  = (const float*)d_in[8];
    const float* rooth = (const float*)d_in[9];

    float* obuf = (float*)d_out;
    float* hT   = (float*)d_ws;     // 32*820*1200 fp32 = ~126 MB (same as proven)

    // leaf projection: relu(x @ W_leaf + b) into obuf h_out scratch rows 0..1279
    {
        dim3 g((1280 + 63) / 64, (400 + 63) / 64);
        gemm_kernel<0><<<g, 256, 0, stream>>>(x, Wl, nullptr, nullptr, blf, obuf,
                                              1280, 400, 1024, 0, 0, 0, 0);
    }
    unit_leaf<<<320, 256, 0, stream>>>(obuf);

    // inside pass
    for (int lv = 0; lv < TLEN; ++lv) {
        int L = TLEN - lv;
        int cb = lv * TLEN - lv * (lv - 1) / 2;
        if (lv > 0)
            compose_kernel<1><<<L * 32, 256, 0, stream>>>(lv, obuf, hT, bin);
        if (lv < TLEN - 1) {
            int M = L * 32;
            dim3 g((M + 63) / 64, (1200 + 63) / 64);
            gemm_kernel<1><<<g, 256, 0, stream>>>(obuf, Win, Win + DD * DD, Sin,
                                                  nullptr, hT, M, 1200, DD, L, cb, 0, 0);
        }
    }

    // prep: hT[:,:,800:1200] = h_in @ W_out_bot for ALL cells (one big GEMM)
    {
        int M = 32 * NCELL;
        dim3 g((M + 63) / 64, (400 + 63) / 64);
        gemm_kernel<1><<<g, 256, 0, stream>>>(obuf, Wout + DD * DD, nullptr, nullptr,
                                              nullptr, hT, M, 400, DD, NCELL, 0, 0, 800);
    }
    root_kernel<<<32, 256, 0, stream>>>(rooth, Wout, Sout, obuf, hT);

    // outside pass
    for (int lv = TLEN - 2; lv >= 0; --lv) {
        int L = TLEN - lv;
        int cb = lv * TLEN - lv * (lv - 1) / 2;
        compose_kernel<0><<<L * 32, 256, 0, stream>>>(lv, obuf, hT, bout);
        if (lv > 0) {
            int M = L * 32;
            dim3 g((M + 63) / 64, (800 + 63) / 64);
            gemm_kernel<1><<<g, 256, 0, stream>>>(obuf, Wout, Sout, nullptr,
                                                  nullptr, hT, M, 800, DD, L, cb, DD + 1, 0);
        }
    }
}

// Round 4
// 4522.359 us; speedup vs baseline: 10.2752x; 1.0032x over previous
//
#include <hip/hip_runtime.h>
#include <math.h>

// DIORA forward, MI355X. B=32, T=40, D_IN=1024, D=400.
// Per-level compose kernel (L*32 blocks) + tiled fp32 GEMM (64x128, BK=32)
// for per-cell transforms. hT (32,820,1200) fp32 in d_ws:
//   inside : [0,400)=h@W_in_top  [400,800)=h@W_in_bot  [800,1200)=h@S_in
//   outside: [0,400)=ho@W_out_top [400,800)=ho@S_out   [800,1200)=h_in@W_out_bot
// obuf (32,820,802): [h_in 400 | s_in 1 | h_out 400 | s_out 1]
// Leaf pre-norm scratch lives in hT[leaf cells][800:1200) (consumed by
// unit_leaf before the lv-0 transform GEMM overwrites it).

#define TLEN 40
#define DD 400
#define NCELL 820
#define STR 802
#define HT 1200

__host__ __device__ __forceinline__ int coff(int l) { return l * TLEN - (l * (l - 1)) / 2; }

// ---------------- 64x128 / BK=32 fp32 GEMM ----------------
// AMODE 0: A = dense row-major (stride K).  AMODE 1: A = obuf cell rows (+hoff).
// C row mapping (both modes): r -> b=r/L, p=r%L, C[((b*NCELL)+cb+p)*HT + co + n].
// B column n selects matrix n/DD from {B0,B1,B2}, col n%DD (N multiple of 16).
template<int AMODE>
__global__ __launch_bounds__(256)
void gemm2(const float* __restrict__ A0,
           const float* __restrict__ B0, const float* __restrict__ B1,
           const float* __restrict__ B2,
           const float* __restrict__ bias,
           float* __restrict__ C,
           int M, int N, int K, int L, int cb, int hoff, int co)
{
    __shared__ float As[32][68];
    __shared__ float Bs[32][132];
    const int tid = threadIdx.x;
    const int bm = blockIdx.x, bn = blockIdx.y;

    // A loader: thread covers row (tid&63), k-chunk of 8 at (tid>>6)*8
    const int ar = tid & 63;
    const int ak = (tid >> 6) * 8;
    const int rg = bm * 64 + ar;
    const float* Ap = nullptr;
    if (rg < M) {
        if (AMODE == 0) Ap = A0 + (size_t)rg * K;
        else { int b = rg / L, p = rg - b * L;
               Ap = A0 + ((size_t)b * NCELL + cb + p) * STR + hoff; }
    }

    // B loader: thread covers k-row (tid>>3), 16-col chunk at (tid&7)*16
    const int bk = tid >> 3;
    const int bc = (tid & 7) * 16;
    const int nb = bn * 128 + bc;
    const float* Bp = nullptr;
    if (nb < N) {
        int mat = nb / DD;
        const float* Bm = (mat == 0) ? B0 : ((mat == 1) ? B1 : B2);
        Bp = Bm + (nb - mat * DD);
    }

    float acc[4][8];
    #pragma unroll
    for (int i = 0; i < 4; ++i)
        #pragma unroll
        for (int j = 0; j < 8; ++j) acc[i][j] = 0.f;

    const int ty = tid >> 4;   // 0..15 row-quad
    const int tx = tid & 15;   // 0..15 col-oct

    for (int k0 = 0; k0 < K; k0 += 32) {
        float av[8];
        if (Ap && (k0 + ak) < K) {
            #pragma unroll
            for (int i = 0; i < 8; ++i) av[i] = Ap[k0 + ak + i];
        } else {
            #pragma unroll
            for (int i = 0; i < 8; ++i) av[i] = 0.f;
        }
        float4 bv[4];
        if (Bp && (k0 + bk) < K) {
            const float* bp = Bp + (size_t)(k0 + bk) * DD;
            bv[0] = *(const float4*)(bp);
            bv[1] = *(const float4*)(bp + 4);
            bv[2] = *(const float4*)(bp + 8);
            bv[3] = *(const float4*)(bp + 12);
        } else {
            bv[0] = bv[1] = bv[2] = bv[3] = make_float4(0.f, 0.f, 0.f, 0.f);
        }
        __syncthreads();
        #pragma unroll
        for (int i = 0; i < 8; ++i) As[ak + i][ar] = av[i];
        *(float4*)&Bs[bk][bc + 0]  = bv[0];
        *(float4*)&Bs[bk][bc + 4]  = bv[1];
        *(float4*)&Bs[bk][bc + 8]  = bv[2];
        *(float4*)&Bs[bk][bc + 12] = bv[3];
        __syncthreads();

        #pragma unroll
        for (int k = 0; k < 32; ++k) {
            float4 a  = *(const float4*)&As[k][ty * 4];
            float4 b0 = *(const float4*)&Bs[k][tx * 8];
            float4 b1 = *(const float4*)&Bs[k][tx * 8 + 4];
            float ai[4] = {a.x, a.y, a.z, a.w};
            float bj[8] = {b0.x, b0.y, b0.z, b0.w, b1.x, b1.y, b1.z, b1.w};
            #pragma unroll
            for (int i = 0; i < 4; ++i)
                #pragma unroll
                for (int j = 0; j < 8; ++j) acc[i][j] += ai[i] * bj[j];
        }
    }

    #pragma unroll
    for (int i = 0; i < 4; ++i) {
        int r = bm * 64 + ty * 4 + i;
        if (r >= M) continue;
        int b = r / L, p = r - b * L;
        size_t crow = ((size_t)b * NCELL + cb + p) * HT + co;
        #pragma unroll
        for (int j = 0; j < 8; ++j) {
            int n = bn * 128 + tx * 8 + j;
            if (n >= N) continue;
            float v = acc[i][j];
            if (bias) v = fmaxf(v + bias[n], 0.f);
            C[crow + n] = v;
        }
    }
}

// ---------------- normalize leaf rows (pre-norm scratch in hT [800:1200)) ----
__global__ __launch_bounds__(256)
void unit_leaf(float* obuf, const float* __restrict__ hT)
{
    int w = threadIdx.x >> 6, lane = threadIdx.x & 63;
    int r = blockIdx.x * 4 + w;                 // 0..1279 = (b, pos)
    int b = r / TLEN, pos = r - b * TLEN;
    const float* t = hT + ((size_t)b * NCELL + pos) * HT + 800;
    float ss = 0.f;
    for (int f = lane; f < DD; f += 64) { float v = t[f]; ss += v * v; }
    #pragma unroll
    for (int o = 32; o; o >>= 1) ss += __shfl_xor(ss, o);
    float rinv = 1.f / (sqrtf(ss) + 1e-8f);
    size_t orow = ((size_t)b * NCELL + pos) * STR;
    for (int f = lane; f < DD; f += 64) obuf[orow + f] = t[f] * rinv;
    if (lane == 0) obuf[orow + DD] = 0.f;       // s_in(leaf)=0
}

// ---------------- per-level compose ----------------
template<int INSIDE>
__global__ __launch_bounds__(256)
void compose_kernel(int lv, float* obuf, const float* __restrict__ hT,
                    const float* __restrict__ bias)
{
    const int nk  = INSIDE ? lv : (TLEN - 1 - lv);
    const int b   = blockIdx.x & 31;
    const int pos = blockIdx.x >> 5;
    const int cell = coff(lv) + pos;
    const int tid = threadIdx.x;

    __shared__ int   i1s[TLEN], i2s[TLEN];
    __shared__ float sbs[TLEN], ps[TLEN];
    __shared__ float hnew[DD];
    __shared__ float red[4];
    __shared__ float sh_snew;

    if (tid < nk) {
        int k = tid, i1, i2;
        if (INSIDE) {
            i1 = coff(k) + pos;
            i2 = coff(lv - k - 1) + pos + k + 1;
        } else {
            if (k < pos) { i1 = coff(lv + k + 1) + pos - k - 1; i2 = coff(k) + pos - k - 1; }
            else         { int j = k - pos; i1 = coff(lv + j + 1) + pos; i2 = coff(j) + pos + lv + 1; }
        }
        i1s[k] = i1; i2s[k] = i2;
    }
    __syncthreads();

    // scores: one 16-lane group per k
    {
        const int g = tid >> 4, gl = tid & 15;
        const int sco = INSIDE ? 800 : 400;
        for (int k = g; k < nk; k += 16) {
            const float* v1 = hT + ((size_t)(b * NCELL) + i1s[k]) * HT + sco;
            const float* v2 = obuf + ((size_t)(b * NCELL) + i2s[k]) * STR;
            float acc = 0.f;
            #pragma unroll 5
            for (int j = gl; j < DD; j += 16) acc += v1[j] * v2[j];
            acc += __shfl_xor(acc, 8);
            acc += __shfl_xor(acc, 4);
            acc += __shfl_xor(acc, 2);
            acc += __shfl_xor(acc, 1);
            if (gl == 0) {
                float st;
                if (INSIDE)
                    st = obuf[((size_t)(b * NCELL) + i1s[k]) * STR + DD]
                       + obuf[((size_t)(b * NCELL) + i2s[k]) * STR + DD];
                else
                    st = obuf[((size_t)(b * NCELL) + i1s[k]) * STR + (STR - 1)]
                       + obuf[((size_t)(b * NCELL) + i2s[k]) * STR + DD];
                sbs[k] = acc + st;
            }
        }
    }
    __syncthreads();

    // softmax (wave 0), also s_new = sum p*sb
    if (tid < 64) {
        float v = (tid < nk) ? sbs[tid] : -INFINITY;
        float m = v;
        #pragma unroll
        for (int o = 32; o; o >>= 1) m = fmaxf(m, __shfl_xor(m, o));
        float e = (tid < nk) ? __expf(v - m) : 0.f;
        float s = e;
        #pragma unroll
        for (int o = 32; o; o >>= 1) s += __shfl_xor(s, o);
        float p = e / s;
        if (tid < nk) ps[tid] = p;
        float pv = (tid < nk) ? p * v : 0.f;
        #pragma unroll
        for (int o = 32; o; o >>= 1) pv += __shfl_xor(pv, o);
        if (tid == 0) sh_snew = pv;
    }
    __syncthreads();

    // h_new = sum_k p_k * relu(hA[i1] + hB[i2] + bias)
    {
        const int bco = INSIDE ? 400 : 800;
        for (int f = tid; f < DD; f += 256) {
            float bf = bias[f];
            float acc = 0.f;
            #pragma unroll 4
            for (int k = 0; k < nk; ++k) {
                float hv = hT[((size_t)(b * NCELL) + i1s[k]) * HT + f]
                         + hT[((size_t)(b * NCELL) + i2s[k]) * HT + bco + f] + bf;
                acc += ps[k] * fmaxf(hv, 0.f);
            }
            hnew[f] = acc;
        }
    }
    __syncthreads();

    // norm
    float ss = 0.f;
    for (int f = tid; f < DD; f += 256) { float v = hnew[f]; ss += v * v; }
    #pragma unroll
    for (int o = 32; o; o >>= 1) ss += __shfl_xor(ss, o);
    if ((tid & 63) == 0) red[tid >> 6] = ss;
    __syncthreads();
    float rinv = 1.f / (sqrtf(red[0] + red[1] + red[2] + red[3]) + 1e-8f);

    const int hoff = INSIDE ? 0 : (DD + 1);
    const int soff = INSIDE ? DD : (STR - 1);
    size_t orow = ((size_t)(b * NCELL) + cell) * STR;
    for (int f = tid; f < DD; f += 256) obuf[orow + hoff + f] = hnew[f] * rinv;
    if (tid == 0) obuf[orow + soff] = sh_snew;
}

// ---------------- root transforms: hT[root][0:800) = [u@Wout_top | u@Sout] ----
__global__ __launch_bounds__(256)
void root_trans(const float* __restrict__ rooth, const float* __restrict__ Wout,
                const float* __restrict__ Sout, float* __restrict__ hT)
{
    const int tid = threadIdx.x;
    __shared__ float u[DD];
    __shared__ float red[4];
    __shared__ float part[4][64];
    float ss = 0.f;
    for (int f = tid; f < DD; f += 256) { float v = rooth[f]; ss += v * v; }
    #pragma unroll
    for (int o = 32; o; o >>= 1) ss += __shfl_xor(ss, o);
    if ((tid & 63) == 0) red[tid >> 6] = ss;
    __syncthreads();
    float rinv = 1.f / (sqrtf(red[0] + red[1] + red[2] + red[3]) + 1e-8f);
    for (int f = tid; f < DD; f += 256) u[f] = rooth[f] * rinv;
    __syncthreads();

    const int w = tid >> 6, lane = tid & 63;
    const int n = blockIdx.x * 64 + lane;
    float acc = 0.f;
    if (n < 800) {
        int mat = n / DD;
        const float* Mp = mat ? Sout : Wout;
        int c = n - mat * DD;
        #pragma unroll 4
        for (int k = w * 100; k < w * 100 + 100; ++k) acc += u[k] * Mp[(size_t)k * DD + c];
    }
    part[w][lane] = acc;
    __syncthreads();
    if (w == 0 && n < 800) {
        float v = part[0][lane] + part[1][lane] + part[2][lane] + part[3][lane];
        for (int b = 0; b < 32; ++b)
            hT[((size_t)b * NCELL + NCELL - 1) * HT + n] = v;
    }
}

// ---------------- root h_out/s_out into obuf ----------------
__global__ __launch_bounds__(256)
void root_write(const float* __restrict__ rooth, float* obuf)
{
    const int b = blockIdx.x;
    const int tid = threadIdx.x;
    __shared__ float red[4];
    float ss = 0.f;
    for (int f = tid; f < DD; f += 256) { float v = rooth[f]; ss += v * v; }
    #pragma unroll
    for (int o = 32; o; o >>= 1) ss += __shfl_xor(ss, o);
    if ((tid & 63) == 0) red[tid >> 6] = ss;
    __syncthreads();
    float rinv = 1.f / (sqrtf(red[0] + red[1] + red[2] + red[3]) + 1e-8f);
    size_t orow = ((size_t)b * NCELL + NCELL - 1) * STR;
    for (int f = tid; f < DD; f += 256) obuf[orow + DD + 1 + f] = rooth[f] * rinv;
    if (tid == 0) obuf[orow + STR - 1] = 0.f;
}

extern "C" void kernel_launch(void* const* d_in, const int* in_sizes, int n_in,
                              void* d_out, int out_size, void* d_ws, size_t ws_size,
                              hipStream_t stream)
{
    const float* x     = (const float*)d_in[0];
    const float* Wl    = (const float*)d_in[1];
    const float* blf   = (const float*)d_in[2];
    const float* Win   = (const float*)d_in[3];
    const float* bin   = (const float*)d_in[4];
    const float* Sin   = (const float*)d_in[5];
    const float* Wout  = (const float*)d_in[6];
    const float* bout  = (const float*)d_in[7];
    const float* Sout  = (const float*)d_in[8];
    const float* rooth = (const float*)d_in[9];

    float* obuf = (float*)d_out;
    float* hT   = (float*)d_ws;     // 32*820*1200 fp32 = ~126 MB

    // leaf projection: relu(x @ W_leaf + b) -> hT[leaf cells][800:1200)
    {
        dim3 g(20, 4);              // M=1280/64, N=400/128
        gemm2<0><<<g, 256, 0, stream>>>(x, Wl, nullptr, nullptr, blf, hT,
                                        1280, 400, 1024, TLEN, 0, 0, 800);
    }
    unit_leaf<<<320, 256, 0, stream>>>(obuf, hT);

    // inside pass
    for (int lv = 0; lv < TLEN; ++lv) {
        int L = TLEN - lv;
        int cb = coff(lv);
        if (lv > 0)
            compose_kernel<1><<<L * 32, 256, 0, stream>>>(lv, obuf, hT, bin);
        if (lv < TLEN - 1) {
            int M = L * 32;
            dim3 g((M + 63) / 64, 10);
            gemm2<1><<<g, 256, 0, stream>>>(obuf, Win, Win + DD * DD, Sin,
                                            nullptr, hT, M, 1200, DD, L, cb, 0, 0);
        }
    }

    // prep: hT[:,:,800:1200) = h_in @ W_out_bot for ALL cells
    {
        dim3 g(410, 4);             // M=26240/64, N=400/128
        gemm2<1><<<g, 256, 0, stream>>>(obuf, Wout + DD * DD, nullptr, nullptr,
                                        nullptr, hT, 32 * NCELL, 400, DD, NCELL, 0, 0, 800);
    }
    root_trans<<<13, 256, 0, stream>>>(rooth, Wout, Sout, hT);
    root_write<<<32, 256, 0, stream>>>(rooth, obuf);

    // outside pass
    for (int lv = TLEN - 2; lv >= 0; --lv) {
        int L = TLEN - lv;
        int cb = coff(lv);
        compose_kernel<0><<<L * 32, 256, 0, stream>>>(lv, obuf, hT, bout);
        if (lv > 0) {
            int M = L * 32;
            dim3 g((M + 63) / 64, 7);
            gemm2<1><<<g, 256, 0, stream>>>(obuf, Wout, Sout, nullptr,
                                            nullptr, hT, M, 800, DD, L, cb, DD + 1, 0);
        }
    }
}

// Round 5
// 4276.612 us; speedup vs baseline: 10.8656x; 1.0575x over previous
//
#include <hip/hip_runtime.h>
#include <math.h>

// DIORA forward, MI355X. B=32, T=40, D_IN=1024, D=400.
// Per-level compose kernel (L*32 blocks) + tiled fp32 GEMM (64x128, BK=32)
// for per-cell transforms. hT (32,820,1200) fp32 in d_ws:
//   inside : [0,400)=h@W_in_top  [400,800)=h@W_in_bot  [800,1200)=h@S_in
//   outside: [0,400)=ho@W_out_top [400,800)=ho@S_out   [800,1200)=h_in@W_out_bot
// obuf (32,820,802): [h_in 400 | s_in 1 | h_out 400 | s_out 1]
// Leaf pre-norm scratch lives in hT[leaf cells][800:1200) (consumed by
// unit_leaf before the lv-0 transform GEMM overwrites it).

#define TLEN 40
#define DD 400
#define NCELL 820
#define STR 802
#define HT 1200

__host__ __device__ __forceinline__ int coff(int l) { return l * TLEN - (l * (l - 1)) / 2; }

// ---------------- 64x128 / BK=32 fp32 GEMM ----------------
// AMODE 0: A = dense row-major (stride K).  AMODE 1: A = obuf cell rows (+hoff).
// C row mapping (both modes): r -> b=r/L, p=r%L, C[((b*NCELL)+cb+p)*HT + co + n].
// B column n selects matrix n/DD from {B0,B1,B2}, col n%DD (N multiple of 16).
// Thread (ty,tx) owns rows ty*4..+3 and cols {tx*4..+3} U {64+tx*4..+3}
// (split halves -> Bs reads are 2-way bank aliasing = free, vs 4-way before).
template<int AMODE>
__global__ __launch_bounds__(256)
void gemm2(const float* __restrict__ A0,
           const float* __restrict__ B0, const float* __restrict__ B1,
           const float* __restrict__ B2,
           const float* __restrict__ bias,
           float* __restrict__ C,
           int M, int N, int K, int L, int cb, int hoff, int co)
{
    __shared__ float As[32][68];
    __shared__ float Bs[32][132];
    const int tid = threadIdx.x;
    const int bm = blockIdx.x, bn = blockIdx.y;

    // A loader: thread covers row (tid&63), k-chunk of 8 at (tid>>6)*8
    const int ar = tid & 63;
    const int ak = (tid >> 6) * 8;
    const int rg = bm * 64 + ar;
    const float* Ap = nullptr;
    if (rg < M) {
        if (AMODE == 0) Ap = A0 + (size_t)rg * K;
        else { int b = rg / L, p = rg - b * L;
               Ap = A0 + ((size_t)b * NCELL + cb + p) * STR + hoff; }
    }

    // B loader: thread covers k-row (tid>>3), 16-col chunk at (tid&7)*16
    const int bk = tid >> 3;
    const int bc = (tid & 7) * 16;
    const int nb = bn * 128 + bc;
    const float* Bp = nullptr;
    if (nb < N) {
        int mat = nb / DD;
        const float* Bm = (mat == 0) ? B0 : ((mat == 1) ? B1 : B2);
        Bp = Bm + (nb - mat * DD);
    }

    float acc[4][8];
    #pragma unroll
    for (int i = 0; i < 4; ++i)
        #pragma unroll
        for (int j = 0; j < 8; ++j) acc[i][j] = 0.f;

    const int ty = tid >> 4;   // 0..15 row-quad
    const int tx = tid & 15;   // 0..15 col-quad (x2 halves)

    for (int k0 = 0; k0 < K; k0 += 32) {
        float av[8];
        if (Ap && (k0 + ak) < K) {
            if (AMODE == 0) {
                float4 p0 = *(const float4*)(Ap + k0 + ak);
                float4 p1 = *(const float4*)(Ap + k0 + ak + 4);
                av[0] = p0.x; av[1] = p0.y; av[2] = p0.z; av[3] = p0.w;
                av[4] = p1.x; av[5] = p1.y; av[6] = p1.z; av[7] = p1.w;
            } else {
                #pragma unroll
                for (int i = 0; i < 8; ++i) av[i] = Ap[k0 + ak + i];
            }
        } else {
            #pragma unroll
            for (int i = 0; i < 8; ++i) av[i] = 0.f;
        }
        float4 bv[4];
        if (Bp && (k0 + bk) < K) {
            const float* bp = Bp + (size_t)(k0 + bk) * DD;
            bv[0] = *(const float4*)(bp);
            bv[1] = *(const float4*)(bp + 4);
            bv[2] = *(const float4*)(bp + 8);
            bv[3] = *(const float4*)(bp + 12);
        } else {
            bv[0] = bv[1] = bv[2] = bv[3] = make_float4(0.f, 0.f, 0.f, 0.f);
        }
        __syncthreads();
        #pragma unroll
        for (int i = 0; i < 8; ++i) As[ak + i][ar] = av[i];
        *(float4*)&Bs[bk][bc + 0]  = bv[0];
        *(float4*)&Bs[bk][bc + 4]  = bv[1];
        *(float4*)&Bs[bk][bc + 8]  = bv[2];
        *(float4*)&Bs[bk][bc + 12] = bv[3];
        __syncthreads();

        #pragma unroll
        for (int k = 0; k < 32; ++k) {
            float4 a  = *(const float4*)&As[k][ty * 4];
            float4 b0 = *(const float4*)&Bs[k][tx * 4];
            float4 b1 = *(const float4*)&Bs[k][64 + tx * 4];
            float ai[4] = {a.x, a.y, a.z, a.w};
            float bj[8] = {b0.x, b0.y, b0.z, b0.w, b1.x, b1.y, b1.z, b1.w};
            #pragma unroll
            for (int i = 0; i < 4; ++i)
                #pragma unroll
                for (int j = 0; j < 8; ++j) acc[i][j] += ai[i] * bj[j];
        }
    }

    #pragma unroll
    for (int i = 0; i < 4; ++i) {
        int r = bm * 64 + ty * 4 + i;
        if (r >= M) continue;
        int b = r / L, p = r - b * L;
        size_t crow = ((size_t)b * NCELL + cb + p) * HT + co;
        #pragma unroll
        for (int j = 0; j < 8; ++j) {
            int n = bn * 128 + ((j < 4) ? (tx * 4 + j) : (64 + tx * 4 + j - 4));
            if (n >= N) continue;
            float v = acc[i][j];
            if (bias) v = fmaxf(v + bias[n], 0.f);
            C[crow + n] = v;
        }
    }
}

// ---------------- normalize leaf rows (pre-norm scratch in hT [800:1200)) ----
__global__ __launch_bounds__(256)
void unit_leaf(float* obuf, const float* __restrict__ hT)
{
    int w = threadIdx.x >> 6, lane = threadIdx.x & 63;
    int r = blockIdx.x * 4 + w;                 // 0..1279 = (b, pos)
    int b = r / TLEN, pos = r - b * TLEN;
    const float* t = hT + ((size_t)b * NCELL + pos) * HT + 800;
    float ss = 0.f;
    for (int f = lane; f < DD; f += 64) { float v = t[f]; ss += v * v; }
    #pragma unroll
    for (int o = 32; o; o >>= 1) ss += __shfl_xor(ss, o);
    float rinv = 1.f / (sqrtf(ss) + 1e-8f);
    size_t orow = ((size_t)b * NCELL + pos) * STR;
    for (int f = lane; f < DD; f += 64) obuf[orow + f] = t[f] * rinv;
    if (lane == 0) obuf[orow + DD] = 0.f;       // s_in(leaf)=0
}

// ---------------- per-level compose ----------------
// Offsets precomputed per k into LDS; score phase = 32 groups x 8 lanes,
// float2 loads (25 exact iters); compose phase = 200 lanes x float2.
template<int INSIDE>
__global__ __launch_bounds__(256)
void compose_kernel(int lv, float* obuf, const float* __restrict__ hT,
                    const float* __restrict__ bias)
{
    const int nk  = INSIDE ? lv : (TLEN - 1 - lv);
    const int b   = blockIdx.x & 31;
    const int pos = blockIdx.x >> 5;
    const int cell = coff(lv) + pos;
    const int tid = threadIdx.x;
    const int bco = INSIDE ? 400 : 800;   // hB column offset in hT
    const int sco = INSIDE ? 800 : 400;   // score-vector column offset in hT
    const int sA  = INSIDE ? DD : (STR - 1);  // s-term offset for i1 in obuf

    __shared__ int   o1s[TLEN], o2s[TLEN], q1s[TLEN], q2s[TLEN];
    __shared__ float sbs[TLEN], ps[TLEN];
    __shared__ float hnew[DD];
    __shared__ float red[4];
    __shared__ float sh_snew;

    if (tid < nk) {
        int k = tid, i1, i2;
        if (INSIDE) {
            i1 = coff(k) + pos;
            i2 = coff(lv - k - 1) + pos + k + 1;
        } else {
            if (k < pos) { i1 = coff(lv + k + 1) + pos - k - 1; i2 = coff(k) + pos - k - 1; }
            else         { int j = k - pos; i1 = coff(lv + j + 1) + pos; i2 = coff(j) + pos + lv + 1; }
        }
        o1s[k] = (b * NCELL + i1) * HT;
        o2s[k] = (b * NCELL + i2) * HT + bco;
        q1s[k] = (b * NCELL + i1) * STR;
        q2s[k] = (b * NCELL + i2) * STR;
    }
    __syncthreads();

    // scores: 32 groups of 8 lanes; float2 dot of length 400
    {
        const int g = tid >> 3, gl = tid & 7;
        for (int k = g; k < nk; k += 32) {
            const float2* v1 = (const float2*)(hT + o1s[k] + sco);
            const float2* v2 = (const float2*)(obuf + q2s[k]);
            float ax = 0.f, ay = 0.f;
            #pragma unroll 5
            for (int j = gl; j < 200; j += 8) {
                float2 a = v1[j], c = v2[j];
                ax += a.x * c.x; ay += a.y * c.y;
            }
            float acc = ax + ay;
            acc += __shfl_xor(acc, 4);
            acc += __shfl_xor(acc, 2);
            acc += __shfl_xor(acc, 1);
            if (gl == 0)
                sbs[k] = acc + obuf[q1s[k] + sA] + obuf[q2s[k] + DD];
        }
    }
    __syncthreads();

    // softmax (wave 0), also s_new = sum p*sb
    if (tid < 64) {
        float v = (tid < nk) ? sbs[tid] : -INFINITY;
        float m = v;
        #pragma unroll
        for (int o = 32; o; o >>= 1) m = fmaxf(m, __shfl_xor(m, o));
        float e = (tid < nk) ? __expf(v - m) : 0.f;
        float s = e;
        #pragma unroll
        for (int o = 32; o; o >>= 1) s += __shfl_xor(s, o);
        float p = e / s;
        if (tid < nk) ps[tid] = p;
        float pv = (tid < nk) ? p * v : 0.f;
        #pragma unroll
        for (int o = 32; o; o >>= 1) pv += __shfl_xor(pv, o);
        if (tid == 0) sh_snew = pv;
    }
    __syncthreads();

    // h_new = sum_k p_k * relu(hA[i1] + hB[i2] + bias), float2, 200 lanes
    if (tid < 200) {
        const int ft = 2 * tid;
        const float bf0 = bias[ft], bf1 = bias[ft + 1];
        float ax = 0.f, ay = 0.f;
        #pragma unroll 4
        for (int k = 0; k < nk; ++k) {
            float2 a = *(const float2*)(hT + o1s[k] + ft);
            float2 c = *(const float2*)(hT + o2s[k] + ft);
            float p = ps[k];
            ax += p * fmaxf(a.x + c.x + bf0, 0.f);
            ay += p * fmaxf(a.y + c.y + bf1, 0.f);
        }
        hnew[ft] = ax; hnew[ft + 1] = ay;
    }
    __syncthreads();

    // norm
    float ss = 0.f;
    for (int f = tid; f < DD; f += 256) { float v = hnew[f]; ss += v * v; }
    #pragma unroll
    for (int o = 32; o; o >>= 1) ss += __shfl_xor(ss, o);
    if ((tid & 63) == 0) red[tid >> 6] = ss;
    __syncthreads();
    float rinv = 1.f / (sqrtf(red[0] + red[1] + red[2] + red[3]) + 1e-8f);

    const int hoff = INSIDE ? 0 : (DD + 1);
    const int soff = INSIDE ? DD : (STR - 1);
    size_t orow = ((size_t)(b * NCELL) + cell) * STR;
    for (int f = tid; f < DD; f += 256) obuf[orow + hoff + f] = hnew[f] * rinv;
    if (tid == 0) obuf[orow + soff] = sh_snew;
}

// ---------------- root transforms: hT[root][0:800) = [u@Wout_top | u@Sout] ----
__global__ __launch_bounds__(256)
void root_trans(const float* __restrict__ rooth, const float* __restrict__ Wout,
                const float* __restrict__ Sout, float* __restrict__ hT)
{
    const int tid = threadIdx.x;
    __shared__ float u[DD];
    __shared__ float red[4];
    __shared__ float part[4][64];
    float ss = 0.f;
    for (int f = tid; f < DD; f += 256) { float v = rooth[f]; ss += v * v; }
    #pragma unroll
    for (int o = 32; o; o >>= 1) ss += __shfl_xor(ss, o);
    if ((tid & 63) == 0) red[tid >> 6] = ss;
    __syncthreads();
    float rinv = 1.f / (sqrtf(red[0] + red[1] + red[2] + red[3]) + 1e-8f);
    for (int f = tid; f < DD; f += 256) u[f] = rooth[f] * rinv;
    __syncthreads();

    const int w = tid >> 6, lane = tid & 63;
    const int n = blockIdx.x * 64 + lane;
    float acc = 0.f;
    if (n < 800) {
        int mat = n / DD;
        const float* Mp = mat ? Sout : Wout;
        int c = n - mat * DD;
        #pragma unroll 4
        for (int k = w * 100; k < w * 100 + 100; ++k) acc += u[k] * Mp[(size_t)k * DD + c];
    }
    part[w][lane] = acc;
    __syncthreads();
    if (w == 0 && n < 800) {
        float v = part[0][lane] + part[1][lane] + part[2][lane] + part[3][lane];
        for (int b = 0; b < 32; ++b)
            hT[((size_t)b * NCELL + NCELL - 1) * HT + n] = v;
    }
}

// ---------------- root h_out/s_out into obuf ----------------
__global__ __launch_bounds__(256)
void root_write(const float* __restrict__ rooth, float* obuf)
{
    const int b = blockIdx.x;
    const int tid = threadIdx.x;
    __shared__ float red[4];
    float ss = 0.f;
    for (int f = tid; f < DD; f += 256) { float v = rooth[f]; ss += v * v; }
    #pragma unroll
    for (int o = 32; o; o >>= 1) ss += __shfl_xor(ss, o);
    if ((tid & 63) == 0) red[tid >> 6] = ss;
    __syncthreads();
    float rinv = 1.f / (sqrtf(red[0] + red[1] + red[2] + red[3]) + 1e-8f);
    size_t orow = ((size_t)b * NCELL + NCELL - 1) * STR;
    for (int f = tid; f < DD; f += 256) obuf[orow + DD + 1 + f] = rooth[f] * rinv;
    if (tid == 0) obuf[orow + STR - 1] = 0.f;
}

extern "C" void kernel_launch(void* const* d_in, const int* in_sizes, int n_in,
                              void* d_out, int out_size, void* d_ws, size_t ws_size,
                              hipStream_t stream)
{
    const float* x     = (const float*)d_in[0];
    const float* Wl    = (const float*)d_in[1];
    const float* blf   = (const float*)d_in[2];
    const float* Win   = (const float*)d_in[3];
    const float* bin   = (const float*)d_in[4];
    const float* Sin   = (const float*)d_in[5];
    const float* Wout  = (const float*)d_in[6];
    const float* bout  = (const float*)d_in[7];
    const float* Sout  = (const float*)d_in[8];
    const float* rooth = (const float*)d_in[9];

    float* obuf = (float*)d_out;
    float* hT   = (float*)d_ws;     // 32*820*1200 fp32 = ~126 MB

    // leaf projection: relu(x @ W_leaf + b) -> hT[leaf cells][800:1200)
    {
        dim3 g(20, 4);              // M=1280/64, N=400/128
        gemm2<0><<<g, 256, 0, stream>>>(x, Wl, nullptr, nullptr, blf, hT,
                                        1280, 400, 1024, TLEN, 0, 0, 800);
    }
    unit_leaf<<<320, 256, 0, stream>>>(obuf, hT);

    // inside pass
    for (int lv = 0; lv < TLEN; ++lv) {
        int L = TLEN - lv;
        int cb = coff(lv);
        if (lv > 0)
            compose_kernel<1><<<L * 32, 256, 0, stream>>>(lv, obuf, hT, bin);
        if (lv < TLEN - 1) {
            int M = L * 32;
            dim3 g((M + 63) / 64, 10);
            gemm2<1><<<g, 256, 0, stream>>>(obuf, Win, Win + DD * DD, Sin,
                                            nullptr, hT, M, 1200, DD, L, cb, 0, 0);
        }
    }

    // prep: hT[:,:,800:1200) = h_in @ W_out_bot for ALL cells
    {
        dim3 g(410, 4);             // M=26240/64, N=400/128
        gemm2<1><<<g, 256, 0, stream>>>(obuf, Wout + DD * DD, nullptr, nullptr,
                                        nullptr, hT, 32 * NCELL, 400, DD, NCELL, 0, 0, 800);
    }
    root_trans<<<13, 256, 0, stream>>>(rooth, Wout, Sout, hT);
    root_write<<<32, 256, 0, stream>>>(rooth, obuf);

    // outside pass
    for (int lv = TLEN - 2; lv >= 0; --lv) {
        int L = TLEN - lv;
        int cb = coff(lv);
        compose_kernel<0><<<L * 32, 256, 0, stream>>>(lv, obuf, hT, bout);
        if (lv > 0) {
            int M = L * 32;
            dim3 g((M + 63) / 64, 7);
            gemm2<1><<<g, 256, 0, stream>>>(obuf, Wout, Sout, nullptr,
                                            nullptr, hT, M, 800, DD, L, cb, DD + 1, 0);
        }
    }
}